// Round 9
// baseline (46.105 us; speedup 1.0000x reference)
//
#include <hip/hip_runtime.h>

#define B_    1024
#define DIM_  512
#define L_    512
#define NOUT  1536
#define G_    32    // interpolation grid points per batch
#define LDA   40    // LDS row stride in ushorts (80 B): 2-way-max bank aliasing
#define NTILE 384   // 24 col-blocks x 16 row-blocks
#define MAGIC 0x3D7FA2C5u

typedef __attribute__((ext_vector_type(8))) short short8;
typedef __attribute__((ext_vector_type(4))) float f32x4;

// packed fp32x2 -> bf16x2 (RNE), one VALU op
__device__ __forceinline__ unsigned int cvtpk(float lo, float hi) {
  unsigned int r;
  asm("v_cvt_pk_bf16_f32 %0, %1, %2" : "=v"(r) : "v"(lo), "v"(hi));
  return r;
}

// Fused: 384 blocks. Each block computes one 64x64 GEMM tile (fused fp32->bf16
// staging, dbuf LDS, MFMA, in_proj epilogue), publishes a per-tile flag with a
// single RELEASE store (one wbl2), then RELAXED-spins (no per-poll cache
// maintenance — R5's bug) on its row-block's 24 flags, one acquire fence, and
// runs rank-1 interpolated attention for its 2-3 batches.
// __launch_bounds__(256,2) => 2 blocks/CU => all 384 co-resident => deadlock-free.
__global__ __launch_bounds__(256, 2) void fused_kernel(
    const float* __restrict__ x, const float* __restrict__ w,
    const float* __restrict__ ipw, const float* __restrict__ ipb,
    const float* __restrict__ ow, const float* __restrict__ ob,
    float* __restrict__ qp, float* __restrict__ kvp,
    unsigned int* __restrict__ flags, float* __restrict__ out)
{
  __shared__ union {
    struct { unsigned short a[2][64 * LDA]; unsigned short b[2][64 * LDA]; } g;  // 20480 B
    struct { float2 kvs[L_]; float2 part2[256]; float fgrid[G_]; float red[8]; } s;
  } sm;

  const int bid = blockIdx.x, tid = threadIdx.x;
  const int cb = bid % 24, rb = bid / 24;
  const int row0 = rb * 64, col0 = cb * 64;
  const int lane = tid & 63, wv = tid >> 6;

  // ---------------- Phase 1: GEMM tile ----------------
  {
    const int sr = tid >> 2, sc = (tid & 3) * 8;
    const float* xg = &x[(size_t)(row0 + sr) * DIM_ + sc];
    const float* wg = &w[(size_t)(col0 + sr) * DIM_ + sc];
    const int soff = sr * LDA + sc;
    const int wr = wv >> 1, wc = wv & 1;
    const int lm = lane & 15, kq = (lane >> 4) * 8;
    const int aoff0 = (wr * 32 + lm) * LDA + kq;
    const int boff0 = (wc * 32 + lm) * LDA + kq;

    f32x4 acc00 = {0,0,0,0}, acc01 = {0,0,0,0}, acc10 = {0,0,0,0}, acc11 = {0,0,0,0};

    float4 al = *(const float4*)(xg), ah = *(const float4*)(xg + 4);
    float4 bl = *(const float4*)(wg), bh = *(const float4*)(wg + 4);
    {
      uint4 av = { cvtpk(al.x,al.y), cvtpk(al.z,al.w), cvtpk(ah.x,ah.y), cvtpk(ah.z,ah.w) };
      uint4 bv = { cvtpk(bl.x,bl.y), cvtpk(bl.z,bl.w), cvtpk(bh.x,bh.y), cvtpk(bh.z,bh.w) };
      *(uint4*)&sm.g.a[0][soff] = av;
      *(uint4*)&sm.g.b[0][soff] = bv;
    }
    __syncthreads();

    int p = 0;
#pragma unroll 2
    for (int k0 = 32; k0 <= DIM_; k0 += 32) {
      if (k0 < DIM_) {   // next chunk's loads early — latency hides under MFMA
        al = *(const float4*)(xg + k0); ah = *(const float4*)(xg + k0 + 4);
        bl = *(const float4*)(wg + k0); bh = *(const float4*)(wg + k0 + 4);
      }
      short8 a0 = *(const short8*)&sm.g.a[p][aoff0];
      short8 a1 = *(const short8*)&sm.g.a[p][aoff0 + 16 * LDA];
      short8 b0 = *(const short8*)&sm.g.b[p][boff0];
      short8 b1 = *(const short8*)&sm.g.b[p][boff0 + 16 * LDA];
      acc00 = __builtin_amdgcn_mfma_f32_16x16x32_bf16(a0, b0, acc00, 0, 0, 0);
      acc01 = __builtin_amdgcn_mfma_f32_16x16x32_bf16(a0, b1, acc01, 0, 0, 0);
      acc10 = __builtin_amdgcn_mfma_f32_16x16x32_bf16(a1, b0, acc10, 0, 0, 0);
      acc11 = __builtin_amdgcn_mfma_f32_16x16x32_bf16(a1, b1, acc11, 0, 0, 0);
      if (k0 < DIM_) {
        uint4 av = { cvtpk(al.x,al.y), cvtpk(al.z,al.w), cvtpk(ah.x,ah.y), cvtpk(ah.z,ah.w) };
        uint4 bv = { cvtpk(bl.x,bl.y), cvtpk(bl.z,bl.w), cvtpk(bh.x,bh.y), cvtpk(bh.z,bh.w) };
        *(uint4*)&sm.g.a[p ^ 1][soff] = av;
        *(uint4*)&sm.g.b[p ^ 1][soff] = bv;
        __syncthreads();
        p ^= 1;
      }
    }

    const float pw0 = ipw[0], pw1 = ipw[1], pw2 = ipw[2];
    const float pb0 = ipb[0], pb1 = ipb[1], pb2 = ipb[2];
    f32x4 accs[2][2] = {{acc00, acc01}, {acc10, acc11}};
#pragma unroll
    for (int cj = 0; cj < 2; ++cj) {
      const int o = col0 + wc * 32 + cj * 16 + lm;
      const int l = o / 3, c = o - 3 * l;
      const float pw = (c == 0) ? pw0 : ((c == 1) ? pw1 : pw2);
      const float pb = (c == 0) ? pb0 : ((c == 1) ? pb1 : pb2);
#pragma unroll
      for (int ri = 0; ri < 2; ++ri)
#pragma unroll
        for (int r = 0; r < 4; ++r) {
          const int row = row0 + wr * 32 + ri * 16 + (lane >> 4) * 4 + r;
          const float v = fmaf(accs[ri][cj][r], pw, pb);
          if (c == 0) qp[(size_t)row * L_ + l] = v;
          else        kvp[(size_t)row * 2 * L_ + 2 * l + (c - 1)] = v;
        }
    }
  }
  __syncthreads();   // all lanes' stores issued+drained before the release
  if (tid == 0)
    __hip_atomic_store(&flags[bid], MAGIC, __ATOMIC_RELEASE, __HIP_MEMORY_SCOPE_AGENT);

  // ------- wait for this row-block's 24 tiles: RELAXED spin, ONE fence -------
  {
    const unsigned int* fl = flags + rb * 24;
    if (tid < 64) {
      const int idx = (tid < 24) ? tid : 0;
      for (;;) {
        unsigned v = __hip_atomic_load(&fl[idx], __ATOMIC_RELAXED, __HIP_MEMORY_SCOPE_AGENT);
        if (__all((tid < 24) ? (v == MAGIC) : 1)) break;
        __builtin_amdgcn_s_sleep(2);
      }
    }
    __syncthreads();
    __builtin_amdgcn_fence(__ATOMIC_ACQUIRE, "agent");   // single L2 inv
  }

  // ---------------- Phase 2: attention for this block's 2-3 batches ---------
  const float w0 = ow[0], b0 = ob[0];
  const float L2E = 1.44269504f;
  const int nb = (cb < 16) ? 3 : 2;
  for (int t = 0; t < nb; ++t) {
    const int b = row0 + cb + t * 24;
    const float2* __restrict__ kvg = (const float2*)&kvp[(size_t)b * 2 * L_];
    float q0 = qp[(size_t)b * L_ + tid];
    float q1 = qp[(size_t)b * L_ + 256 + tid];
    float2 t0 = kvg[tid], t1 = kvg[tid + 256];
    sm.s.kvs[tid] = t0; sm.s.kvs[tid + 256] = t1;

    float qmn = fminf(q0, q1), qmx = fmaxf(q0, q1);
#pragma unroll
    for (int off = 32; off; off >>= 1) {
      qmn = fminf(qmn, __shfl_xor(qmn, off));
      qmx = fmaxf(qmx, __shfl_xor(qmx, off));
    }
    if ((tid & 63) == 0) { sm.s.red[tid >> 6] = qmn; sm.s.red[4 + (tid >> 6)] = qmx; }
    __syncthreads();
    qmn = fminf(fminf(sm.s.red[0], sm.s.red[1]), fminf(sm.s.red[2], sm.s.red[3]));
    qmx = fmaxf(fmaxf(sm.s.red[4], sm.s.red[5]), fmaxf(sm.s.red[6], sm.s.red[7]));

    const float range = qmx - qmn;
    const float hstep = range * (1.f / (G_ - 1));
    const int g   = tid & (G_ - 1);      // grid point 0..31
    const int seg = tid >> 5;            // j-segment 0..7 (64 terms each)
    const float gq = (qmn + hstep * (float)g) * L2E;
    float num = 0.f, den = 0.f;
    const float4* kv4 = (const float4*)&sm.s.kvs[seg * 64];
#pragma unroll 4
    for (int j = 0; j < 32; ++j) {
      float4 pr = kv4[j];                // k,v,k,v (half-wave-uniform broadcast)
      float e0 = __builtin_amdgcn_exp2f(gq * pr.x);
      den += e0; num = fmaf(e0, pr.y, num);
      float e1 = __builtin_amdgcn_exp2f(gq * pr.z);
      den += e1; num = fmaf(e1, pr.w, num);
    }
    sm.s.part2[tid] = make_float2(num, den);
    __syncthreads();
    if (tid < G_) {
      float nsum = 0.f, dsum = 0.f;
#pragma unroll
      for (int s = 0; s < 8; ++s) {
        float2 pp = sm.s.part2[tid + 32 * s];
        nsum += pp.x; dsum += pp.y;
      }
      sm.s.fgrid[tid] = nsum / dsum;
    }
    __syncthreads();

    const float inv_h = (range > 1e-20f) ? (float)(G_ - 1) / range : 0.f;
#pragma unroll
    for (int ii = 0; ii < 2; ++ii) {
      const float q = ii ? q1 : q0;
      float u = (q - qmn) * inv_h;
      u = fminf(fmaxf(u, 0.f), (float)(G_ - 1));
      int gi = (int)u;
      gi = min(gi, G_ - 2);
      const float tt = u - (float)gi;
      const float p0 = sm.s.fgrid[max(gi - 1, 0)];
      const float p1 = sm.s.fgrid[gi];
      const float p2 = sm.s.fgrid[gi + 1];
      const float p3 = sm.s.fgrid[min(gi + 2, G_ - 1)];
      // Catmull-Rom
      const float f = 0.5f * (2.f * p1 + tt * ((p2 - p0)
                    + tt * ((2.f * p0 - 5.f * p1 + 4.f * p2 - p3)
                    + tt * (3.f * (p1 - p2) + p3 - p0))));
      const int i = ii * 256 + tid;
      out[(size_t)b * L_ + i] = fmaf(f, w0, b0) + x[(size_t)b * L_ + i];
    }
    __syncthreads();   // protect part2/fgrid before next batch reuses LDS
  }
}

extern "C" void kernel_launch(void* const* d_in, const int* in_sizes, int n_in,
                              void* d_out, int out_size, void* d_ws, size_t ws_size,
                              hipStream_t stream) {
  const float* x     = (const float*)d_in[0];
  const float* qkv_w = (const float*)d_in[1];
  const float* ipw   = (const float*)d_in[2];
  const float* ipb   = (const float*)d_in[3];
  const float* ow    = (const float*)d_in[4];
  const float* ob    = (const float*)d_in[5];
  float* out = (float*)d_out;

  char* ws = (char*)d_ws;
  float*        qp    = (float*)(ws);                  // 2.0 MB
  float*        kvp   = (float*)(ws + 2097152);        // 4.0 MB
  unsigned int* flags = (unsigned int*)(ws + 6291456); // 384 words

  fused_kernel<<<dim3(NTILE), dim3(256), 0, stream>>>(
      x, qkv_w, ipw, ipb, ow, ob, qp, kvp, flags, out);
}

// Round 10
// 20.045 us; speedup vs baseline: 2.3001x; 2.3001x over previous
//
#include <hip/hip_runtime.h>

#define B_   1024
#define DIM_ 512
#define L_   512
#define NOUT 1536
#define G_   32    // interpolation grid points per batch
#define LDA  40    // LDS row stride in ushorts (80 B): 2-way-max bank aliasing

typedef __attribute__((ext_vector_type(8))) short short8;
typedef __attribute__((ext_vector_type(4))) float f32x4;

// packed fp32x2 -> bf16x2 (RNE), one VALU op
__device__ __forceinline__ unsigned int cvtpk(float lo, float hi) {
  unsigned int r;
  asm("v_cvt_pk_bf16_f32 %0, %1, %2" : "=v"(r) : "v"(lo), "v"(hi));
  return r;
}

struct Chunk { float4 al, ah, bl, bh; };

// ---------------- Kernel A: fused cvt + MFMA GEMM + in_proj ----------------
// C[b,o] = sum_k x[b,k]*w[o,k]. 64x64 tile/block, BK=32, 4 waves each owning
// a 32x32 quadrant. 2-deep register prefetch: chunk k+2's global loads are
// issued while computing chunk k, so the vmcnt wait before the LDS write of
// chunk k+1 finds the data already arrived (~1.5 phases in flight > L2 lat).
__global__ __launch_bounds__(256) void gemm_kernel(
    const float* __restrict__ x, const float* __restrict__ w,
    const float* __restrict__ ipw, const float* __restrict__ ipb,
    float* __restrict__ qp, float* __restrict__ kvp)
{
  __shared__ unsigned short aT[2][64 * LDA];   // 10 KB
  __shared__ unsigned short bT[2][64 * LDA];   // 10 KB

  const int tid  = threadIdx.x;
  const int lane = tid & 63;
  const int wv   = tid >> 6;
  const int row0 = blockIdx.y * 64;
  const int col0 = blockIdx.x * 64;

  // staging assignment: row sr (0..63), k-chunk sc (0,8,16,24)
  const int sr = tid >> 2;
  const int sc = (tid & 3) * 8;
  const float* xg = &x[(size_t)(row0 + sr) * DIM_ + sc];
  const float* wg = &w[(size_t)(col0 + sr) * DIM_ + sc];
  const int soff = sr * LDA + sc;

  // fragment read assignment
  const int wr = wv >> 1, wc = wv & 1;
  const int lm = lane & 15;
  const int kq = (lane >> 4) * 8;
  const int aoff0 = (wr * 32 + lm) * LDA + kq;
  const int boff0 = (wc * 32 + lm) * LDA + kq;

  f32x4 acc00 = {0,0,0,0}, acc01 = {0,0,0,0}, acc10 = {0,0,0,0}, acc11 = {0,0,0,0};

#define LOADC(dst, k0) do { \
    (dst).al = *(const float4*)(xg + (k0));     \
    (dst).ah = *(const float4*)(xg + (k0) + 4); \
    (dst).bl = *(const float4*)(wg + (k0));     \
    (dst).bh = *(const float4*)(wg + (k0) + 4); } while (0)
#define STORE_LDS(src, buf) do { \
    uint4 av_ = { cvtpk((src).al.x,(src).al.y), cvtpk((src).al.z,(src).al.w), \
                  cvtpk((src).ah.x,(src).ah.y), cvtpk((src).ah.z,(src).ah.w) }; \
    uint4 bv_ = { cvtpk((src).bl.x,(src).bl.y), cvtpk((src).bl.z,(src).bl.w), \
                  cvtpk((src).bh.x,(src).bh.y), cvtpk((src).bh.z,(src).bh.w) }; \
    *(uint4*)&aT[buf][soff] = av_; \
    *(uint4*)&bT[buf][soff] = bv_; } while (0)

  Chunk c0, c1, c2;
  LOADC(c0, 0);
  STORE_LDS(c0, 0);
  LOADC(c1, 32);          // in flight across the barrier + chunk-0 compute
  __syncthreads();

  int p = 0;
#pragma unroll 2
  for (int kc = 0; kc < 16; ++kc) {
    if (kc + 2 < 16) LOADC(c2, (kc + 2) * 32);   // issue 2 steps ahead
    short8 a0 = *(const short8*)&aT[p][aoff0];
    short8 a1 = *(const short8*)&aT[p][aoff0 + 16 * LDA];
    short8 b0 = *(const short8*)&bT[p][boff0];
    short8 b1 = *(const short8*)&bT[p][boff0 + 16 * LDA];
    acc00 = __builtin_amdgcn_mfma_f32_16x16x32_bf16(a0, b0, acc00, 0, 0, 0);
    acc01 = __builtin_amdgcn_mfma_f32_16x16x32_bf16(a0, b1, acc01, 0, 0, 0);
    acc10 = __builtin_amdgcn_mfma_f32_16x16x32_bf16(a1, b0, acc10, 0, 0, 0);
    acc11 = __builtin_amdgcn_mfma_f32_16x16x32_bf16(a1, b1, acc11, 0, 0, 0);
    if (kc < 15) {
      STORE_LDS(c1, p ^ 1);   // c1 arrived long ago; vmcnt wait ~free
      __syncthreads();
      p ^= 1;
      c1 = c2;
    }
  }
#undef LOADC
#undef STORE_LDS

  const float pw0 = ipw[0], pw1 = ipw[1], pw2 = ipw[2];
  const float pb0 = ipb[0], pb1 = ipb[1], pb2 = ipb[2];
  f32x4 accs[2][2] = {{acc00, acc01}, {acc10, acc11}};
#pragma unroll
  for (int cj = 0; cj < 2; ++cj) {
    const int o = col0 + wc * 32 + cj * 16 + lm;
    const int l = o / 3;
    const int c = o - 3 * l;
    const float pw = (c == 0) ? pw0 : ((c == 1) ? pw1 : pw2);
    const float pb = (c == 0) ? pb0 : ((c == 1) ? pb1 : pb2);
#pragma unroll
    for (int ri = 0; ri < 2; ++ri) {
#pragma unroll
      for (int r = 0; r < 4; ++r) {
        const int row = row0 + wr * 32 + ri * 16 + (lane >> 4) * 4 + r;
        const float v = fmaf(accs[ri][cj][r], pw, pb);
        if (c == 0) qp[(size_t)row * L_ + l] = v;
        else        kvp[(size_t)row * 2 * L_ + 2 * l + (c - 1)] = v;
      }
    }
  }
}

// ---------------- Kernel B: rank-1 attention via per-batch interpolation ---
// f(q) = sum_j exp(q k_j) v_j / sum_j exp(q k_j): evaluate on G_=32-pt grid
// over [qmin,qmax], Catmull-Rom interpolate the 512 rows. One block per batch.
__global__ __launch_bounds__(256) void attn_kernel(
    const float* __restrict__ qp, const float* __restrict__ kvp,
    const float* __restrict__ x, const float* __restrict__ ow,
    const float* __restrict__ ob, float* __restrict__ out)
{
  __shared__ float2 kvs[L_];      // 4 KB
  __shared__ float2 part2[256];   // 2 KB
  __shared__ float  fgrid[G_];
  __shared__ float  red[8];
  const int b = blockIdx.x, tid = threadIdx.x;
  const float2* __restrict__ kvg = (const float2*)&kvp[(size_t)b * 2 * L_];

  float q0 = qp[(size_t)b * L_ + tid];
  float q1 = qp[(size_t)b * L_ + 256 + tid];
  float2 t0 = kvg[tid], t1 = kvg[tid + 256];
  kvs[tid] = t0; kvs[tid + 256] = t1;

  float qmn = fminf(q0, q1), qmx = fmaxf(q0, q1);
#pragma unroll
  for (int off = 32; off; off >>= 1) {
    qmn = fminf(qmn, __shfl_xor(qmn, off));
    qmx = fmaxf(qmx, __shfl_xor(qmx, off));
  }
  if ((tid & 63) == 0) { red[tid >> 6] = qmn; red[4 + (tid >> 6)] = qmx; }
  __syncthreads();
  qmn = fminf(fminf(red[0], red[1]), fminf(red[2], red[3]));
  qmx = fmaxf(fmaxf(red[4], red[5]), fmaxf(red[6], red[7]));

  const float L2E = 1.44269504f;
  const float range = qmx - qmn;
  const float hstep = range * (1.f / (G_ - 1));
  const int g   = tid & (G_ - 1);      // grid point 0..31
  const int seg = tid >> 5;            // j-segment 0..7 (64 terms each)
  const float gq = (qmn + hstep * (float)g) * L2E;
  float num = 0.f, den = 0.f;
  const float4* kv4 = (const float4*)&kvs[seg * 64];
#pragma unroll 4
  for (int j = 0; j < 32; ++j) {
    float4 pr = kv4[j];                // k,v,k,v (half-wave-uniform broadcast)
    float e0 = __builtin_amdgcn_exp2f(gq * pr.x);
    den += e0; num = fmaf(e0, pr.y, num);
    float e1 = __builtin_amdgcn_exp2f(gq * pr.z);
    den += e1; num = fmaf(e1, pr.w, num);
  }
  part2[tid] = make_float2(num, den);
  __syncthreads();
  if (tid < G_) {
    float nsum = 0.f, dsum = 0.f;
#pragma unroll
    for (int s = 0; s < 8; ++s) {
      float2 pp = part2[tid + 32 * s];
      nsum += pp.x; dsum += pp.y;
    }
    fgrid[tid] = nsum / dsum;
  }
  __syncthreads();

  const float inv_h = (range > 1e-20f) ? (float)(G_ - 1) / range : 0.f;
  const float w0 = ow[0], b0 = ob[0];
#pragma unroll
  for (int ii = 0; ii < 2; ++ii) {
    const float q = ii ? q1 : q0;
    float u = (q - qmn) * inv_h;
    u = fminf(fmaxf(u, 0.f), (float)(G_ - 1));
    int gi = (int)u;
    gi = min(gi, G_ - 2);
    const float t = u - (float)gi;
    const float p0 = fgrid[max(gi - 1, 0)];
    const float p1 = fgrid[gi];
    const float p2 = fgrid[gi + 1];
    const float p3 = fgrid[min(gi + 2, G_ - 1)];
    // Catmull-Rom
    const float f = 0.5f * (2.f * p1 + t * ((p2 - p0)
                  + t * ((2.f * p0 - 5.f * p1 + 4.f * p2 - p3)
                  + t * (3.f * (p1 - p2) + p3 - p0))));
    const int i = ii * 256 + tid;
    out[(size_t)b * L_ + i] = fmaf(f, w0, b0) + x[(size_t)b * L_ + i];
  }
}

extern "C" void kernel_launch(void* const* d_in, const int* in_sizes, int n_in,
                              void* d_out, int out_size, void* d_ws, size_t ws_size,
                              hipStream_t stream) {
  const float* x     = (const float*)d_in[0];
  const float* qkv_w = (const float*)d_in[1];
  const float* ipw   = (const float*)d_in[2];
  const float* ipb   = (const float*)d_in[3];
  const float* ow    = (const float*)d_in[4];
  const float* ob    = (const float*)d_in[5];
  float* out = (float*)d_out;

  char* ws = (char*)d_ws;
  float* qp  = (float*)(ws);            // 2.0 MB
  float* kvp = (float*)(ws + 2097152);  // 4.0 MB

  dim3 gA(NOUT / 64, B_ / 64);          // 24 x 16 = 384 blocks
  gemm_kernel<<<gA, dim3(256), 0, stream>>>(x, qkv_w, ipw, ipb, qp, kvp);

  attn_kernel<<<dim3(B_), dim3(256), 0, stream>>>(qp, kvp, x, ow, ob, out);
}

// Round 11
// 19.796 us; speedup vs baseline: 2.3289x; 1.0125x over previous
//
#include <hip/hip_runtime.h>

#define B_   1024
#define DIM_ 512
#define L_   512
#define NOUT 1536
#define G_   32    // interpolation grid points per batch
#define LDA  40    // LDS row stride in ushorts (80 B): 2-way-max bank aliasing

typedef __attribute__((ext_vector_type(8))) short short8;
typedef __attribute__((ext_vector_type(4))) float f32x4;

// packed fp32x2 -> bf16x2 (RNE), one VALU op
__device__ __forceinline__ unsigned int cvtpk(float lo, float hi) {
  unsigned int r;
  asm("v_cvt_pk_bf16_f32 %0, %1, %2" : "=v"(r) : "v"(lo), "v"(hi));
  return r;
}

struct Chunk { float4 al, ah, bl, bh; };

// ---------------- Kernel A: fused cvt + MFMA GEMM + in_proj ----------------
// C[b,o] = sum_k x[b,k]*w[o,k]. 64x64 tile/block, BK=32, 4 waves each owning
// a 32x32 quadrant. 2-deep register prefetch (R10). XCD-aware block swizzle:
// xcd = bid&7 owns 3 column-tiles (48 blocks) -> per-XCD L2 working set =
// x (2 MB) + w panel (384 KB) = 2.4 MB < 4 MB L2 (unswizzled: 5 MB, thrash).
__global__ __launch_bounds__(256) void gemm_kernel(
    const float* __restrict__ x, const float* __restrict__ w,
    const float* __restrict__ ipw, const float* __restrict__ ipb,
    float* __restrict__ qp, float* __restrict__ kvp)
{
  __shared__ unsigned short aT[2][64 * LDA];   // 10 KB
  __shared__ unsigned short bT[2][64 * LDA];   // 10 KB

  const int tid  = threadIdx.x;
  const int lane = tid & 63;
  const int wv   = tid >> 6;
  const int bid  = blockIdx.x;
  const int xcd  = bid & 7, slot = bid >> 3;   // HW: xcd = dispatch_id % 8
  const int cb   = xcd * 3 + (slot >> 4);      // 3 col-tiles per XCD
  const int rb   = slot & 15;
  const int row0 = rb * 64;
  const int col0 = cb * 64;

  // staging assignment: row sr (0..63), k-chunk sc (0,8,16,24)
  const int sr = tid >> 2;
  const int sc = (tid & 3) * 8;
  const float* xg = &x[(size_t)(row0 + sr) * DIM_ + sc];
  const float* wg = &w[(size_t)(col0 + sr) * DIM_ + sc];
  const int soff = sr * LDA + sc;

  // fragment read assignment
  const int wr = wv >> 1, wc = wv & 1;
  const int lm = lane & 15;
  const int kq = (lane >> 4) * 8;
  const int aoff0 = (wr * 32 + lm) * LDA + kq;
  const int boff0 = (wc * 32 + lm) * LDA + kq;

  f32x4 acc00 = {0,0,0,0}, acc01 = {0,0,0,0}, acc10 = {0,0,0,0}, acc11 = {0,0,0,0};

#define LOADC(dst, k0) do { \
    (dst).al = *(const float4*)(xg + (k0));     \
    (dst).ah = *(const float4*)(xg + (k0) + 4); \
    (dst).bl = *(const float4*)(wg + (k0));     \
    (dst).bh = *(const float4*)(wg + (k0) + 4); } while (0)
#define STORE_LDS(src, buf) do { \
    uint4 av_ = { cvtpk((src).al.x,(src).al.y), cvtpk((src).al.z,(src).al.w), \
                  cvtpk((src).ah.x,(src).ah.y), cvtpk((src).ah.z,(src).ah.w) }; \
    uint4 bv_ = { cvtpk((src).bl.x,(src).bl.y), cvtpk((src).bl.z,(src).bl.w), \
                  cvtpk((src).bh.x,(src).bh.y), cvtpk((src).bh.z,(src).bh.w) }; \
    *(uint4*)&aT[buf][soff] = av_; \
    *(uint4*)&bT[buf][soff] = bv_; } while (0)

  Chunk c0, c1, c2;
  LOADC(c0, 0);
  STORE_LDS(c0, 0);
  LOADC(c1, 32);          // in flight across the barrier + chunk-0 compute
  __syncthreads();

  int p = 0;
#pragma unroll 2
  for (int kc = 0; kc < 16; ++kc) {
    if (kc + 2 < 16) LOADC(c2, (kc + 2) * 32);   // issue 2 steps ahead
    short8 a0 = *(const short8*)&aT[p][aoff0];
    short8 a1 = *(const short8*)&aT[p][aoff0 + 16 * LDA];
    short8 b0 = *(const short8*)&bT[p][boff0];
    short8 b1 = *(const short8*)&bT[p][boff0 + 16 * LDA];
    acc00 = __builtin_amdgcn_mfma_f32_16x16x32_bf16(a0, b0, acc00, 0, 0, 0);
    acc01 = __builtin_amdgcn_mfma_f32_16x16x32_bf16(a0, b1, acc01, 0, 0, 0);
    acc10 = __builtin_amdgcn_mfma_f32_16x16x32_bf16(a1, b0, acc10, 0, 0, 0);
    acc11 = __builtin_amdgcn_mfma_f32_16x16x32_bf16(a1, b1, acc11, 0, 0, 0);
    if (kc < 15) {
      STORE_LDS(c1, p ^ 1);   // c1 arrived long ago; vmcnt wait ~free
      __syncthreads();
      p ^= 1;
      c1 = c2;
    }
  }
#undef LOADC
#undef STORE_LDS

  const float pw0 = ipw[0], pw1 = ipw[1], pw2 = ipw[2];
  const float pb0 = ipb[0], pb1 = ipb[1], pb2 = ipb[2];
  f32x4 accs[2][2] = {{acc00, acc01}, {acc10, acc11}};
#pragma unroll
  for (int cj = 0; cj < 2; ++cj) {
    const int o = col0 + wc * 32 + cj * 16 + lm;
    const int l = o / 3;
    const int c = o - 3 * l;
    const float pw = (c == 0) ? pw0 : ((c == 1) ? pw1 : pw2);
    const float pb = (c == 0) ? pb0 : ((c == 1) ? pb1 : pb2);
#pragma unroll
    for (int ri = 0; ri < 2; ++ri) {
#pragma unroll
      for (int r = 0; r < 4; ++r) {
        const int row = row0 + wr * 32 + ri * 16 + (lane >> 4) * 4 + r;
        const float v = fmaf(accs[ri][cj][r], pw, pb);
        if (c == 0) qp[(size_t)row * L_ + l] = v;
        else        kvp[(size_t)row * 2 * L_ + 2 * l + (c - 1)] = v;
      }
    }
  }
}

// ---------------- Kernel B: rank-1 attention via per-batch interpolation ---
// f(q) = sum_j exp(q k_j) v_j / sum_j exp(q k_j): evaluate on G_=32-pt grid
// over [qmin,qmax], Catmull-Rom interpolate the 512 rows. One block per batch.
__global__ __launch_bounds__(256) void attn_kernel(
    const float* __restrict__ qp, const float* __restrict__ kvp,
    const float* __restrict__ x, const float* __restrict__ ow,
    const float* __restrict__ ob, float* __restrict__ out)
{
  __shared__ float2 kvs[L_];      // 4 KB
  __shared__ float2 part2[256];   // 2 KB
  __shared__ float  fgrid[G_];
  __shared__ float  red[8];
  const int b = blockIdx.x, tid = threadIdx.x;
  const float2* __restrict__ kvg = (const float2*)&kvp[(size_t)b * 2 * L_];

  float q0 = qp[(size_t)b * L_ + tid];
  float q1 = qp[(size_t)b * L_ + 256 + tid];
  // hoist residual loads above the first barrier so they issue early
  // (barriers pin global loads; unhoisted they serialize after the exp loop)
  const float xres0 = x[(size_t)b * L_ + tid];
  const float xres1 = x[(size_t)b * L_ + 256 + tid];
  const float w0 = ow[0], b0 = ob[0];
  float2 t0 = kvg[tid], t1 = kvg[tid + 256];
  kvs[tid] = t0; kvs[tid + 256] = t1;

  float qmn = fminf(q0, q1), qmx = fmaxf(q0, q1);
#pragma unroll
  for (int off = 32; off; off >>= 1) {
    qmn = fminf(qmn, __shfl_xor(qmn, off));
    qmx = fmaxf(qmx, __shfl_xor(qmx, off));
  }
  if ((tid & 63) == 0) { red[tid >> 6] = qmn; red[4 + (tid >> 6)] = qmx; }
  __syncthreads();
  qmn = fminf(fminf(red[0], red[1]), fminf(red[2], red[3]));
  qmx = fmaxf(fmaxf(red[4], red[5]), fmaxf(red[6], red[7]));

  const float L2E = 1.44269504f;
  const float range = qmx - qmn;
  const float hstep = range * (1.f / (G_ - 1));
  const int g   = tid & (G_ - 1);      // grid point 0..31
  const int seg = tid >> 5;            // j-segment 0..7 (64 terms each)
  const float gq = (qmn + hstep * (float)g) * L2E;
  float num = 0.f, den = 0.f;
  const float4* kv4 = (const float4*)&kvs[seg * 64];
#pragma unroll 4
  for (int j = 0; j < 32; ++j) {
    float4 pr = kv4[j];                // k,v,k,v (half-wave-uniform broadcast)
    float e0 = __builtin_amdgcn_exp2f(gq * pr.x);
    den += e0; num = fmaf(e0, pr.y, num);
    float e1 = __builtin_amdgcn_exp2f(gq * pr.z);
    den += e1; num = fmaf(e1, pr.w, num);
  }
  part2[tid] = make_float2(num, den);
  __syncthreads();
  if (tid < G_) {
    float nsum = 0.f, dsum = 0.f;
#pragma unroll
    for (int s = 0; s < 8; ++s) {
      float2 pp = part2[tid + 32 * s];
      nsum += pp.x; dsum += pp.y;
    }
    fgrid[tid] = nsum / dsum;
  }
  __syncthreads();

  const float inv_h = (range > 1e-20f) ? (float)(G_ - 1) / range : 0.f;
#pragma unroll
  for (int ii = 0; ii < 2; ++ii) {
    const float q = ii ? q1 : q0;
    float u = (q - qmn) * inv_h;
    u = fminf(fmaxf(u, 0.f), (float)(G_ - 1));
    int gi = (int)u;
    gi = min(gi, G_ - 2);
    const float t = u - (float)gi;
    const float p0 = fgrid[max(gi - 1, 0)];
    const float p1 = fgrid[gi];
    const float p2 = fgrid[gi + 1];
    const float p3 = fgrid[min(gi + 2, G_ - 1)];
    // Catmull-Rom
    const float f = 0.5f * (2.f * p1 + t * ((p2 - p0)
                  + t * ((2.f * p0 - 5.f * p1 + 4.f * p2 - p3)
                  + t * (3.f * (p1 - p2) + p3 - p0))));
    const int i = ii * 256 + tid;
    out[(size_t)b * L_ + i] = fmaf(f, w0, b0) + (ii ? xres1 : xres0);
  }
}

extern "C" void kernel_launch(void* const* d_in, const int* in_sizes, int n_in,
                              void* d_out, int out_size, void* d_ws, size_t ws_size,
                              hipStream_t stream) {
  const float* x     = (const float*)d_in[0];
  const float* qkv_w = (const float*)d_in[1];
  const float* ipw   = (const float*)d_in[2];
  const float* ipb   = (const float*)d_in[3];
  const float* ow    = (const float*)d_in[4];
  const float* ob    = (const float*)d_in[5];
  float* out = (float*)d_out;

  char* ws = (char*)d_ws;
  float* qp  = (float*)(ws);            // 2.0 MB
  float* kvp = (float*)(ws + 2097152);  // 4.0 MB

  gemm_kernel<<<dim3(384), dim3(256), 0, stream>>>(x, qkv_w, ipw, ipb, qp, kvp);

  attn_kernel<<<dim3(B_), dim3(256), 0, stream>>>(qp, kvp, x, ow, ob, out);
}